// Round 7
// baseline (2104.089 us; speedup 1.0000x reference)
//
#include <hip/hip_runtime.h>

typedef unsigned short u16;
typedef unsigned int   u32;

#define N_P 200000
#define N_A 100000
#define DD  64
#define HH  32
#define NE  1000000
#define NBP 782          // paper buckets / row-blocks: (N_P+255)/256
#define NBA 391          // author buckets: (N_A+255)/256
#define EB  3907         // (NE+255)/256
#define NBUKT (NBP + NBP + NBA)   // 1955

// ---------- bf16 helpers (RNE) ----------
__device__ inline float bf2f(u16 u) { return __uint_as_float(((u32)u) << 16); }
__device__ inline u16 f2bf(float f) {
    u32 u = __float_as_uint(f);
    u += 0x7fffu + ((u >> 16) & 1u);
    return (u16)(u >> 16);
}

// ---------- bucket histogram (LDS-privatized) ----------
__global__ __launch_bounds__(256) void hist_k(
    const int* __restrict__ d0, const int* __restrict__ d1, const int* __restrict__ d2,
    int* __restrict__ cnt3) {
    __shared__ int h[NBP];
    int rel = blockIdx.y;
    const int* d = rel == 0 ? d0 : rel == 1 ? d1 : d2;
    int nb = (rel == 2) ? NBA : NBP;
    int base = rel * NBP;
    int t = threadIdx.x;
    for (int i = t; i < nb; i += 256) h[i] = 0;
    __syncthreads();
    for (int e = blockIdx.x * 256 + t; e < NE; e += gridDim.x * 256)
        atomicAdd(&h[d[e] >> 8], 1);
    __syncthreads();
    for (int i = t; i < nb; i += 256)
        if (h[i]) atomicAdd(&cnt3[base + i], h[i]);
}

// ---------- one-block scan over buckets (per relation) ----------
__global__ __launch_bounds__(256) void scan_k(
    const int* __restrict__ cnt3,
    int* __restrict__ off_c, int* __restrict__ off_w, int* __restrict__ off_r,
    int* __restrict__ cur_c, int* __restrict__ cur_w, int* __restrict__ cur_r) {
    __shared__ int s[256];
    int t = threadIdx.x;
    for (int rel = 0; rel < 3; ++rel) {
        int nb = (rel == 2) ? NBA : NBP;
        const int* src = cnt3 + rel * NBP;
        int* off = rel == 0 ? off_c : rel == 1 ? off_w : off_r;
        int* cur = rel == 0 ? cur_c : rel == 1 ? cur_w : cur_r;
        int v[4]; int tot = 0;
#pragma unroll
        for (int i = 0; i < 4; ++i) {
            int idx = t * 4 + i;
            v[i] = (idx < nb) ? src[idx] : 0;
            tot += v[i];
        }
        s[t] = tot;
        __syncthreads();
        for (int o = 1; o < 256; o <<= 1) {
            int u = (t >= o) ? s[t - o] : 0;
            __syncthreads();
            s[t] += u;
            __syncthreads();
        }
        int run = s[t] - tot;
#pragma unroll
        for (int i = 0; i < 4; ++i) {
            int idx = t * 4 + i;
            if (idx < nb) { off[idx] = run; cur[idx] = run; }
            run += v[i];
        }
        if (t == 0) off[nb] = NE;
        __syncthreads();
    }
}

// ---------- bucket fill: packed (src<<8 | dloc) ----------
__global__ __launch_bounds__(256) void bfill_k(
    const int* __restrict__ s0, const int* __restrict__ d0,
    const int* __restrict__ s1, const int* __restrict__ d1,
    const int* __restrict__ s2, const int* __restrict__ d2,
    int* __restrict__ cur_c, int* __restrict__ cur_w, int* __restrict__ cur_r,
    u32* __restrict__ pc, u32* __restrict__ pw, u32* __restrict__ pr) {
    int rel = blockIdx.y;
    const int *src, *dst; int* cur; u32* pairs;
    if (rel == 0)      { src = s0; dst = d0; cur = cur_c; pairs = pc; }
    else if (rel == 1) { src = s1; dst = d1; cur = cur_w; pairs = pw; }
    else               { src = s2; dst = d2; cur = cur_r; pairs = pr; }
    int e = blockIdx.x * 256 + threadIdx.x;
    if (e < NE) {
        int d = dst[e];
        int pos = atomicAdd(&cur[d >> 8], 1);
        pairs[pos] = ((u32)src[e] << 8) | (u32)(d & 255);
    }
}

// ---------- weight prep ----------
__global__ __launch_bounds__(256) void prep_sum_k(
    const float* __restrict__ W1rc, const float* __restrict__ W1rw,
    const float* __restrict__ b1c, const float* __restrict__ b1w,
    const float* __restrict__ W2rc, const float* __restrict__ W2rw,
    const float* __restrict__ b2c, const float* __restrict__ b2w,
    float* __restrict__ W1s, float* __restrict__ W2s,
    float* __restrict__ b1s, float* __restrict__ b2s) {
    int t = blockIdx.x * 256 + threadIdx.x;
    if (t < DD * HH) W1s[t] = W1rc[t] + W1rw[t];
    if (t < HH * HH) W2s[t] = W2rc[t] + W2rw[t];
    if (t < HH) {
        b1s[t] = b1c[t] + b1w[t];
        b2s[t] = b2c[t] + b2w[t];
    }
}

// ---------- dense transform core (wave-uniform W -> scalar loads) ----------
template <int K>
__device__ inline void mm_uni(const float* xr, const float* __restrict__ W, float* acc) {
#pragma unroll 8
    for (int k = 0; k < K; ++k) {
        float xk = xr[k];
#pragma unroll
        for (int c = 0; c < HH; ++c) acc[c] = fmaf(xk, W[k * HH + c], acc[c]);
    }
}

// ---------- LDS-staged fully-coalesced stores (sbuf: >=256*33 floats) ----------
__device__ inline void coop_store_bf16(float* sbuf, int t, const float* acc,
                                       bool valid, int nv, u16* grow) {
    if (valid) {
        u32* sp = (u32*)sbuf + t * 17;
#pragma unroll
        for (int i = 0; i < 16; ++i)
            sp[i] = (u32)f2bf(acc[2 * i]) | ((u32)f2bf(acc[2 * i + 1]) << 16);
    }
    __syncthreads();
    u32* g = (u32*)grow;
#pragma unroll
    for (int p = 0; p < 4; ++p) {
        int i = p * 256 + t;
        int row = i >> 2, off = (i & 3) * 4;
        if (row < nv) {
            const u32* q = (const u32*)sbuf + row * 17 + off;
            *(uint4*)(g + (size_t)i * 4) = make_uint4(q[0], q[1], q[2], q[3]);
        }
    }
    __syncthreads();
}

__device__ inline void coop_store_f32(float* sbuf, int t, const float* acc,
                                      bool valid, int nv, float* grow) {
    if (valid) {
        float* sp = sbuf + t * 33;
#pragma unroll
        for (int c = 0; c < HH; ++c) sp[c] = acc[c];
    }
    __syncthreads();
#pragma unroll
    for (int p = 0; p < 8; ++p) {
        int i = p * 256 + t;
        int row = i >> 3, off = (i & 7) * 4;
        if (row < nv) {
            const float* q = sbuf + row * 33 + off;
            *(float4*)(grow + (size_t)i * 4) = make_float4(q[0], q[1], q[2], q[3]);
        }
    }
    __syncthreads();
}

// ---------- layer-1 transforms, paper+author fused (round-6, unchanged) ----------
__global__ __launch_bounds__(256) void t1_k(
    const float* __restrict__ xp, const float* __restrict__ xa,
    const float* __restrict__ Wlc, const float* __restrict__ Wlr,
    const float* __restrict__ W1s, const float* __restrict__ b1s,
    const float* __restrict__ Wlw, const float* __restrict__ Wrr,
    const float* __restrict__ b1r,
    u16* __restrict__ y_pc, u16* __restrict__ y_pr, u16* __restrict__ y_aw,
    float* __restrict__ hp, float* __restrict__ ha) {
    __shared__ float sbuf[256 * 33];
    int t = threadIdx.x;
    float xr[DD];
    float acc[HH];
    if (blockIdx.x < NBP) {
        int row0 = blockIdx.x * 256;
        int nv = min(256, N_P - row0);
        bool valid = t < nv;
        if (valid) {
            const float4* xv = (const float4*)(xp + (size_t)(row0 + t) * DD);
#pragma unroll
            for (int i = 0; i < DD / 4; ++i) {
                float4 v = xv[i];
                xr[4 * i] = v.x; xr[4 * i + 1] = v.y; xr[4 * i + 2] = v.z; xr[4 * i + 3] = v.w;
            }
        }
#pragma unroll
        for (int c = 0; c < HH; ++c) acc[c] = 0.f;
        if (valid) mm_uni<DD>(xr, Wlc, acc);
        coop_store_bf16(sbuf, t, acc, valid, nv, y_pc + (size_t)row0 * HH);
#pragma unroll
        for (int c = 0; c < HH; ++c) acc[c] = 0.f;
        if (valid) mm_uni<DD>(xr, Wlr, acc);
        coop_store_bf16(sbuf, t, acc, valid, nv, y_pr + (size_t)row0 * HH);
#pragma unroll
        for (int c = 0; c < HH; ++c) acc[c] = b1s[c];
        if (valid) mm_uni<DD>(xr, W1s, acc);
        coop_store_f32(sbuf, t, acc, valid, nv, hp + (size_t)row0 * HH);
    } else {
        int row0 = (blockIdx.x - NBP) * 256;
        int nv = min(256, N_A - row0);
        bool valid = t < nv;
        if (valid) {
            const float4* xv = (const float4*)(xa + (size_t)(row0 + t) * DD);
#pragma unroll
            for (int i = 0; i < DD / 4; ++i) {
                float4 v = xv[i];
                xr[4 * i] = v.x; xr[4 * i + 1] = v.y; xr[4 * i + 2] = v.z; xr[4 * i + 3] = v.w;
            }
        }
#pragma unroll
        for (int c = 0; c < HH; ++c) acc[c] = 0.f;
        if (valid) mm_uni<DD>(xr, Wlw, acc);
        coop_store_bf16(sbuf, t, acc, valid, nv, y_aw + (size_t)row0 * HH);
#pragma unroll
        for (int c = 0; c < HH; ++c) acc[c] = b1r[c];
        if (valid) mm_uni<DD>(xr, Wrr, acc);
        coop_store_f32(sbuf, t, acc, valid, nv, ha + (size_t)row0 * HH);
    }
}

// ---------- bucket-local pair aggregation into LDS (stride 33, conflict-free) ----------
__device__ inline void agg_pairs(const u32* __restrict__ pairs, int n0, int n1,
                                 const u16* __restrict__ y,
                                 float* acc, int* cnt, int t) {
    int lane = t & 31;
    int hw = t >> 5;                 // 8 half-waves/block
    int j = n0 + hw;
    for (; j + 24 < n1; j += 32) {   // unroll 4: 4 gathers in flight per half-wave
        u32 p0 = pairs[j], p1 = pairs[j + 8], p2 = pairs[j + 16], p3 = pairs[j + 24];
        float v0 = bf2f(y[(size_t)(p0 >> 8) * HH + lane]);
        float v1 = bf2f(y[(size_t)(p1 >> 8) * HH + lane]);
        float v2 = bf2f(y[(size_t)(p2 >> 8) * HH + lane]);
        float v3 = bf2f(y[(size_t)(p3 >> 8) * HH + lane]);
        atomicAdd(&acc[(p0 & 255) * 33 + lane], v0);
        atomicAdd(&acc[(p1 & 255) * 33 + lane], v1);
        atomicAdd(&acc[(p2 & 255) * 33 + lane], v2);
        atomicAdd(&acc[(p3 & 255) * 33 + lane], v3);
        if (lane == 0) {
            atomicAdd(&cnt[p0 & 255], 1);
            atomicAdd(&cnt[p1 & 255], 1);
            atomicAdd(&cnt[p2 & 255], 1);
            atomicAdd(&cnt[p3 & 255], 1);
        }
    }
    for (; j < n1; j += 8) {
        u32 p = pairs[j];
        float v = bf2f(y[(size_t)(p >> 8) * HH + lane]);
        atomicAdd(&acc[(p & 255) * 33 + lane], v);
        if (lane == 0) atomicAdd(&cnt[p & 255], 1);
    }
}

__device__ inline void zero_acc(float* acc, int* cnt, int t) {
    for (int i = t; i < 256 * 33; i += 256) acc[i] = 0.f;
    cnt[t] = 0;
}

// ---------- paper L1 agg (cites+writes) fused with paper L2 transform ----------
__global__ __launch_bounds__(256) void aggP1_k(
    const u16* __restrict__ y_pc, const u16* __restrict__ y_aw,
    const u32* __restrict__ pc, const u32* __restrict__ pw,
    const int* __restrict__ off_c, const int* __restrict__ off_w,
    const float* __restrict__ Wl, const float* __restrict__ Ws,
    const float* __restrict__ bs,
    float* __restrict__ hp, u16* __restrict__ z_p) {
    __shared__ float acc[256 * 33];
    __shared__ int cnt[256];
    int t = threadIdx.x, b = blockIdx.x;
    int row0 = b << 8;
    int nv = min(256, N_P - row0);
    bool valid = t < nv;
    float xr[HH];

    zero_acc(acc, cnt, t);
    __syncthreads();
    agg_pairs(pc, off_c[b], off_c[b + 1], y_pc, acc, cnt, t);
    __syncthreads();
    if (valid) {
        float ic = 1.f / (float)max(cnt[t], 1);
#pragma unroll
        for (int c = 0; c < HH; ++c) xr[c] = acc[t * 33 + c] * ic;
    }
    __syncthreads();
    zero_acc(acc, cnt, t);
    __syncthreads();
    agg_pairs(pw, off_w[b], off_w[b + 1], y_aw, acc, cnt, t);
    __syncthreads();
    if (valid) {
        float iw = 1.f / (float)max(cnt[t], 1);
        const float* hv = hp + (size_t)(row0 + t) * HH;
#pragma unroll
        for (int c = 0; c < HH; ++c) {
            float u = hv[c] + xr[c] + acc[t * 33 + c] * iw;
            xr[c] = u > 0.f ? u : 0.f;
        }
    }
    __syncthreads();   // all acc reads done before sbuf reuse

    float o[HH];
#pragma unroll
    for (int c = 0; c < HH; ++c) o[c] = 0.f;
    if (valid) mm_uni<HH>(xr, Wl, o);
    coop_store_bf16(acc, t, o, valid, nv, z_p + (size_t)row0 * HH);
#pragma unroll
    for (int c = 0; c < HH; ++c) o[c] = bs[c];
    if (valid) mm_uni<HH>(xr, Ws, o);
    coop_store_f32(acc, t, o, valid, nv, hp + (size_t)row0 * HH);  // in-place: block owns rows
}

// ---------- author L1 agg (rev) fused with author L2 transform ----------
__global__ __launch_bounds__(256) void aggA1_k(
    const u16* __restrict__ y_pr, const u32* __restrict__ pr,
    const int* __restrict__ off_r,
    const float* __restrict__ Wl,
    const float* __restrict__ ha, u16* __restrict__ z_a) {
    __shared__ float acc[256 * 33];
    __shared__ int cnt[256];
    int t = threadIdx.x, b = blockIdx.x;
    int row0 = b << 8;
    int nv = min(256, N_A - row0);
    bool valid = t < nv;
    float xr[HH];

    zero_acc(acc, cnt, t);
    __syncthreads();
    agg_pairs(pr, off_r[b], off_r[b + 1], y_pr, acc, cnt, t);
    __syncthreads();
    if (valid) {
        float iv = 1.f / (float)max(cnt[t], 1);
        const float* hv = ha + (size_t)(row0 + t) * HH;
#pragma unroll
        for (int c = 0; c < HH; ++c) {
            float u = hv[c] + acc[t * 33 + c] * iv;
            xr[c] = u > 0.f ? u : 0.f;
        }
    }
    __syncthreads();

    float o[HH];
#pragma unroll
    for (int c = 0; c < HH; ++c) o[c] = 0.f;
    if (valid) mm_uni<HH>(xr, Wl, o);
    coop_store_bf16(acc, t, o, valid, nv, z_a + (size_t)row0 * HH);
}

// ---------- paper L2 agg (cites+writes on z) -> d_out ----------
__global__ __launch_bounds__(256) void aggP2_k(
    const u16* __restrict__ z_p, const u16* __restrict__ z_a,
    const u32* __restrict__ pc, const u32* __restrict__ pw,
    const int* __restrict__ off_c, const int* __restrict__ off_w,
    const float* __restrict__ hp, float* __restrict__ out) {
    __shared__ float acc[256 * 33];
    __shared__ int cnt[256];
    int t = threadIdx.x, b = blockIdx.x;
    int row0 = b << 8;
    int nv = min(256, N_P - row0);
    bool valid = t < nv;
    float xr[HH];

    zero_acc(acc, cnt, t);
    __syncthreads();
    agg_pairs(pc, off_c[b], off_c[b + 1], z_p, acc, cnt, t);
    __syncthreads();
    if (valid) {
        float ic = 1.f / (float)max(cnt[t], 1);
#pragma unroll
        for (int c = 0; c < HH; ++c) xr[c] = acc[t * 33 + c] * ic;
    }
    __syncthreads();
    zero_acc(acc, cnt, t);
    __syncthreads();
    agg_pairs(pw, off_w[b], off_w[b + 1], z_a, acc, cnt, t);
    __syncthreads();
    float o[HH];
    if (valid) {
        float iw = 1.f / (float)max(cnt[t], 1);
        const float* hv = hp + (size_t)(row0 + t) * HH;
#pragma unroll
        for (int c = 0; c < HH; ++c) o[c] = hv[c] + xr[c] + acc[t * 33 + c] * iw;
    }
    __syncthreads();
    coop_store_f32(acc, t, o, valid, nv, out + (size_t)row0 * HH);
}

extern "C" void kernel_launch(void* const* d_in, const int* in_sizes, int n_in,
                              void* d_out, int out_size, void* d_ws, size_t ws_size,
                              hipStream_t stream) {
    const float* x_p  = (const float*)d_in[0];
    const float* x_a  = (const float*)d_in[1];
    const int* c_src  = (const int*)d_in[2];
    const int* c_dst  = (const int*)d_in[3];
    const int* w_src  = (const int*)d_in[4];
    const int* w_dst  = (const int*)d_in[5];
    const int* r_src  = (const int*)d_in[6];
    const int* r_dst  = (const int*)d_in[7];
    const float* W1l_c = (const float*)d_in[8];
    const float* W1r_c = (const float*)d_in[9];
    const float* b1_c  = (const float*)d_in[10];
    const float* W1l_w = (const float*)d_in[11];
    const float* W1r_w = (const float*)d_in[12];
    const float* b1_w  = (const float*)d_in[13];
    const float* W1l_r = (const float*)d_in[14];
    const float* W1r_r = (const float*)d_in[15];
    const float* b1_r  = (const float*)d_in[16];
    const float* W2l_c = (const float*)d_in[17];
    const float* W2r_c = (const float*)d_in[18];
    const float* b2_c  = (const float*)d_in[19];
    const float* W2l_w = (const float*)d_in[20];
    const float* W2r_w = (const float*)d_in[21];
    const float* b2_w  = (const float*)d_in[22];

    // ---- workspace ----
    int* wsi   = (int*)d_ws;
    int* cnt3  = wsi;                       // NBUKT (memset to 0)
    int* off_c = cnt3 + NBUKT;              // NBP+1
    int* off_w = off_c + (NBP + 1);         // NBP+1
    int* off_r = off_w + (NBP + 1);         // NBA+1
    int* cur_c = off_r + (NBA + 1);         // NBP
    int* cur_w = cur_c + NBP;               // NBP
    int* cur_r = cur_w + NBP;               // NBA
    u32* pc    = (u32*)(cur_r + NBA);       // NE
    u32* pw    = pc + NE;                   // NE
    u32* pr    = pw + NE;                   // NE
    uintptr_t fbase = ((uintptr_t)(pr + NE) + 15) & ~(uintptr_t)15;
    float* W1s = (float*)fbase;             // 2048
    float* W2s = W1s + DD * HH;             // 1024
    float* b1s = W2s + HH * HH;             // 32
    float* b2s = b1s + HH;                  // 32
    float* hp  = b2s + HH;                  // N_P*32 f32
    float* ha  = hp + (size_t)N_P * HH;     // N_A*32 f32
    u16* y_pc  = (u16*)(ha + (size_t)N_A * HH); // N_P*32 bf16
    u16* y_pr  = y_pc + (size_t)N_P * HH;       // N_P*32
    u16* y_aw  = y_pr + (size_t)N_P * HH;       // N_A*32
    u16* z_p   = y_aw + (size_t)N_A * HH;       // N_P*32 (fresh: aggP1 reads y_pc)
    u16* z_a   = y_aw;                          // reuse: aggA1 reads only y_pr
    float* outp = (float*)d_out;

    const size_t need = ((uintptr_t)(z_p + (size_t)N_P * HH)) - (uintptr_t)d_ws;
    if (ws_size < need) return;  // fail loudly, not OOB

    hipMemsetAsync(cnt3, 0, NBUKT * sizeof(int), stream);
    prep_sum_k<<<8, 256, 0, stream>>>(W1r_c, W1r_w, b1_c, b1_w, W2r_c, W2r_w, b2_c, b2_w,
                                      W1s, W2s, b1s, b2s);

    hist_k<<<dim3(128, 3), 256, 0, stream>>>(c_dst, w_dst, r_dst, cnt3);
    scan_k<<<1, 256, 0, stream>>>(cnt3, off_c, off_w, off_r, cur_c, cur_w, cur_r);
    bfill_k<<<dim3(EB, 3), 256, 0, stream>>>(c_src, c_dst, w_src, w_dst, r_src, r_dst,
                                             cur_c, cur_w, cur_r, pc, pw, pr);

    t1_k<<<NBP + NBA, 256, 0, stream>>>(x_p, x_a, W1l_c, W1l_r, W1s, b1s,
                                        W1l_w, W1r_r, b1_r, y_pc, y_pr, y_aw, hp, ha);
    aggP1_k<<<NBP, 256, 0, stream>>>(y_pc, y_aw, pc, pw, off_c, off_w,
                                     W2l_c, W2s, b2s, hp, z_p);
    aggA1_k<<<NBA, 256, 0, stream>>>(y_pr, pr, off_r, W2l_w, ha, z_a);
    aggP2_k<<<NBP, 256, 0, stream>>>(z_p, z_a, pc, pw, off_c, off_w, hp, outp);
}

// Round 8
// 666.936 us; speedup vs baseline: 3.1549x; 3.1549x over previous
//
#include <hip/hip_runtime.h>

typedef unsigned short u16;
typedef unsigned int   u32;
typedef short sv2 __attribute__((ext_vector_type(2)));

#define N_P 200000
#define N_A 100000
#define DD  64
#define HH  32
#define NE  1000000
#define NBP 782          // (N_P+255)/256
#define NBA 391          // (N_A+255)/256
#define EB  3907         // (NE+255)/256

#if defined(__has_builtin)
#if __has_builtin(__builtin_amdgcn_global_atomic_fadd_v2bf16)
#define HAS_PK_BF16 1
#endif
#endif
#ifndef HAS_PK_BF16
#define HAS_PK_BF16 0
#endif

// ---------- bf16 helpers (RNE) ----------
__device__ inline float bf2f(u16 u) { return __uint_as_float(((u32)u) << 16); }
__device__ inline u16 f2bf(float f) {
    u32 u = __float_as_uint(f);
    u += 0x7fffu + ((u >> 16) & 1u);
    return (u16)(u >> 16);
}

// packed bf16x2 atomic add: HW instr when available, CAS emulation otherwise
__device__ inline void pk_add_bf16(u32* p, float lo, float hi) {
#if HAS_PK_BF16
    union { u32 u; sv2 s; } c;
    c.u = (u32)f2bf(lo) | ((u32)f2bf(hi) << 16);
    __builtin_amdgcn_global_atomic_fadd_v2bf16(
        (__attribute__((address_space(1))) sv2*)(unsigned long long)p, c.s);
#else
    u32 old = *p, assumed;
    do {
        assumed = old;
        float alo = bf2f((u16)(assumed & 0xffffu)) + lo;
        float ahi = bf2f((u16)(assumed >> 16)) + hi;
        u32 nv = (u32)f2bf(alo) | ((u32)f2bf(ahi) << 16);
        old = atomicCAS(p, assumed, nv);
    } while (old != assumed);
#endif
}

// ---------- degree counting / reciprocals ----------
__global__ __launch_bounds__(256) void count3_k(
    const int* __restrict__ d0, const int* __restrict__ d1, const int* __restrict__ d2,
    int* __restrict__ g0, int* __restrict__ g1, int* __restrict__ g2) {
    int e = blockIdx.x * 256 + threadIdx.x;
    const int* d; int* g;
    if (blockIdx.y == 0)      { d = d0; g = g0; }
    else if (blockIdx.y == 1) { d = d1; g = g1; }
    else                      { d = d2; g = g2; }
    if (e < NE) atomicAdd(&g[d[e]], 1);
}

__global__ __launch_bounds__(256) void deg2inv_k(int* __restrict__ buf, int n) {
    int i = blockIdx.x * 256 + threadIdx.x;
    if (i < n) {
        int d = buf[i];
        float v = 1.0f / (float)(d < 1 ? 1 : d);
        buf[i] = __float_as_int(v);
    }
}

// ---------- weight prep ----------
__global__ __launch_bounds__(256) void prep_sum_k(
    const float* __restrict__ W1rc, const float* __restrict__ W1rw,
    const float* __restrict__ b1c, const float* __restrict__ b1w,
    const float* __restrict__ W2rc, const float* __restrict__ W2rw,
    const float* __restrict__ b2c, const float* __restrict__ b2w,
    float* __restrict__ W1s, float* __restrict__ W2s,
    float* __restrict__ b1s, float* __restrict__ b2s) {
    int t = blockIdx.x * 256 + threadIdx.x;
    if (t < DD * HH) W1s[t] = W1rc[t] + W1rw[t];
    if (t < HH * HH) W2s[t] = W2rc[t] + W2rw[t];
    if (t < HH) {
        b1s[t] = b1c[t] + b1w[t];
        b2s[t] = b2c[t] + b2w[t];
    }
}

// ---------- dense transform core (wave-uniform W -> scalar loads) ----------
template <int K>
__device__ inline void mm_uni(const float* xr, const float* __restrict__ W, float* acc) {
#pragma unroll 8
    for (int k = 0; k < K; ++k) {
        float xk = xr[k];
#pragma unroll
        for (int c = 0; c < HH; ++c) acc[c] = fmaf(xk, W[k * HH + c], acc[c]);
    }
}

// ---------- LDS-staged fully-coalesced stores ----------
__device__ inline void coop_store_bf16(float* sbuf, int t, const float* acc,
                                       bool valid, int nv, u16* grow) {
    if (valid) {
        u32* sp = (u32*)sbuf + t * 17;
#pragma unroll
        for (int i = 0; i < 16; ++i)
            sp[i] = (u32)f2bf(acc[2 * i]) | ((u32)f2bf(acc[2 * i + 1]) << 16);
    }
    __syncthreads();
    u32* g = (u32*)grow;
#pragma unroll
    for (int p = 0; p < 4; ++p) {
        int i = p * 256 + t;
        int row = i >> 2, off = (i & 3) * 4;
        if (row < nv) {
            const u32* q = (const u32*)sbuf + row * 17 + off;
            *(uint4*)(g + (size_t)i * 4) = make_uint4(q[0], q[1], q[2], q[3]);
        }
    }
    __syncthreads();
}

__device__ inline void coop_store_f32(float* sbuf, int t, const float* acc,
                                      bool valid, int nv, float* grow) {
    if (valid) {
        float* sp = sbuf + t * 33;
#pragma unroll
        for (int c = 0; c < HH; ++c) sp[c] = acc[c];
    }
    __syncthreads();
#pragma unroll
    for (int p = 0; p < 8; ++p) {
        int i = p * 256 + t;
        int row = i >> 3, off = (i & 7) * 4;
        if (row < nv) {
            const float* q = sbuf + row * 33 + off;
            *(float4*)(grow + (size_t)i * 4) = make_float4(q[0], q[1], q[2], q[3]);
        }
    }
    __syncthreads();
}

// ---------- layer-1 transforms, paper+author fused ----------
// paper: y_pc=x@W1l_c, y_pr=x@W1l_r (bf16 msgs); hb_p = bf16(x@W1s+b1s)  [L1 acc init=self]
// author: y_aw=x@W1l_w; hb_a = bf16(x@W1r_r+b1_r)
__global__ __launch_bounds__(256) void t1_k(
    const float* __restrict__ xp, const float* __restrict__ xa,
    const float* __restrict__ Wlc, const float* __restrict__ Wlr,
    const float* __restrict__ W1s, const float* __restrict__ b1s,
    const float* __restrict__ Wlw, const float* __restrict__ Wrr,
    const float* __restrict__ b1r,
    u16* __restrict__ y_pc, u16* __restrict__ y_pr, u16* __restrict__ y_aw,
    u16* __restrict__ hb_p, u16* __restrict__ hb_a) {
    __shared__ float sbuf[256 * 17];   // bf16 staging only (u32 stride 17)
    int t = threadIdx.x;
    float xr[DD];
    float acc[HH];
    if (blockIdx.x < NBP) {
        int row0 = blockIdx.x * 256;
        int nv = min(256, N_P - row0);
        bool valid = t < nv;
        if (valid) {
            const float4* xv = (const float4*)(xp + (size_t)(row0 + t) * DD);
#pragma unroll
            for (int i = 0; i < DD / 4; ++i) {
                float4 v = xv[i];
                xr[4 * i] = v.x; xr[4 * i + 1] = v.y; xr[4 * i + 2] = v.z; xr[4 * i + 3] = v.w;
            }
        }
#pragma unroll
        for (int c = 0; c < HH; ++c) acc[c] = 0.f;
        if (valid) mm_uni<DD>(xr, Wlc, acc);
        coop_store_bf16(sbuf, t, acc, valid, nv, y_pc + (size_t)row0 * HH);
#pragma unroll
        for (int c = 0; c < HH; ++c) acc[c] = 0.f;
        if (valid) mm_uni<DD>(xr, Wlr, acc);
        coop_store_bf16(sbuf, t, acc, valid, nv, y_pr + (size_t)row0 * HH);
#pragma unroll
        for (int c = 0; c < HH; ++c) acc[c] = b1s[c];
        if (valid) mm_uni<DD>(xr, W1s, acc);
        coop_store_bf16(sbuf, t, acc, valid, nv, hb_p + (size_t)row0 * HH);
    } else {
        int row0 = (blockIdx.x - NBP) * 256;
        int nv = min(256, N_A - row0);
        bool valid = t < nv;
        if (valid) {
            const float4* xv = (const float4*)(xa + (size_t)(row0 + t) * DD);
#pragma unroll
            for (int i = 0; i < DD / 4; ++i) {
                float4 v = xv[i];
                xr[4 * i] = v.x; xr[4 * i + 1] = v.y; xr[4 * i + 2] = v.z; xr[4 * i + 3] = v.w;
            }
        }
#pragma unroll
        for (int c = 0; c < HH; ++c) acc[c] = 0.f;
        if (valid) mm_uni<DD>(xr, Wlw, acc);
        coop_store_bf16(sbuf, t, acc, valid, nv, y_aw + (size_t)row0 * HH);
#pragma unroll
        for (int c = 0; c < HH; ++c) acc[c] = b1r[c];
        if (valid) mm_uni<DD>(xr, Wrr, acc);
        coop_store_bf16(sbuf, t, acc, valid, nv, hb_a + (size_t)row0 * HH);
    }
}

// ---------- L1 scatter: acc[dst] += y[src]*inv[dst], packed bf16 atomics ----------
// 16 lanes/edge (2 channels each); edge row = one 64B line
__global__ __launch_bounds__(256) void scat3_k(
    const u16* __restrict__ yc, const u16* __restrict__ ya, const u16* __restrict__ yr,
    const int* __restrict__ cs, const int* __restrict__ cd,
    const int* __restrict__ wsrc, const int* __restrict__ wd,
    const int* __restrict__ rs, const int* __restrict__ rd,
    const float* __restrict__ inv_c, const float* __restrict__ inv_w,
    const float* __restrict__ inv_r,
    u32* __restrict__ hb_p, u32* __restrict__ hb_a) {
    int rel = blockIdx.y;
    const u16* y; const int* src; const int* dst; const float* inv; u32* acc;
    if (rel == 0)      { y = yc; src = cs;   dst = cd; inv = inv_c; acc = hb_p; }
    else if (rel == 1) { y = ya; src = wsrc; dst = wd; inv = inv_w; acc = hb_p; }
    else               { y = yr; src = rs;   dst = rd; inv = inv_r; acc = hb_a; }
    int t = threadIdx.x;
    int e = blockIdx.x * 16 + (t >> 4);
    int lane = t & 15;
    if (e >= NE) return;
    int s = src[e], d = dst[e];
    float iv = inv[d];
    u32 m = *(const u32*)(y + (size_t)s * HH + lane * 2);
    float lo = bf2f((u16)(m & 0xffffu)) * iv;
    float hi = bf2f((u16)(m >> 16)) * iv;
    pk_add_bf16(acc + (size_t)d * (HH / 2) + lane, lo, hi);
}

// ---------- layer-2 transforms ----------
// paper: r=relu(hb_p); z_p=r@W2l_c (bf16 msgs); hp2=r@W2s+b2s (f32 self)
// author: z_a=relu(hb_a)@W2l_w
__global__ __launch_bounds__(256) void t2_k(
    const u32* __restrict__ hb_p, const u32* __restrict__ hb_a,
    const float* __restrict__ Wlc, const float* __restrict__ W2s,
    const float* __restrict__ b2s, const float* __restrict__ Wlw,
    u16* __restrict__ z_p, u16* __restrict__ z_a, float* __restrict__ hp2) {
    __shared__ float sbuf[256 * 33];
    int t = threadIdx.x;
    float xr[HH];
    float acc[HH];
    if (blockIdx.x < NBP) {
        int row0 = blockIdx.x * 256;
        int nv = min(256, N_P - row0);
        bool valid = t < nv;
        if (valid) {
            const uint4* hv = (const uint4*)(hb_p + (size_t)(row0 + t) * (HH / 2));
#pragma unroll
            for (int i = 0; i < 4; ++i) {
                uint4 q = hv[i];
                u32 qq[4] = {q.x, q.y, q.z, q.w};
#pragma unroll
                for (int j = 0; j < 4; ++j) {
                    float lo = bf2f((u16)(qq[j] & 0xffffu));
                    float hi = bf2f((u16)(qq[j] >> 16));
                    xr[i * 8 + j * 2]     = lo > 0.f ? lo : 0.f;
                    xr[i * 8 + j * 2 + 1] = hi > 0.f ? hi : 0.f;
                }
            }
        }
#pragma unroll
        for (int c = 0; c < HH; ++c) acc[c] = 0.f;
        if (valid) mm_uni<HH>(xr, Wlc, acc);
        coop_store_bf16(sbuf, t, acc, valid, nv, z_p + (size_t)row0 * HH);
#pragma unroll
        for (int c = 0; c < HH; ++c) acc[c] = b2s[c];
        if (valid) mm_uni<HH>(xr, W2s, acc);
        coop_store_f32(sbuf, t, acc, valid, nv, hp2 + (size_t)row0 * HH);
    } else {
        int row0 = (blockIdx.x - NBP) * 256;
        int nv = min(256, N_A - row0);
        bool valid = t < nv;
        if (valid) {
            const uint4* hv = (const uint4*)(hb_a + (size_t)(row0 + t) * (HH / 2));
#pragma unroll
            for (int i = 0; i < 4; ++i) {
                uint4 q = hv[i];
                u32 qq[4] = {q.x, q.y, q.z, q.w};
#pragma unroll
                for (int j = 0; j < 4; ++j) {
                    float lo = bf2f((u16)(qq[j] & 0xffffu));
                    float hi = bf2f((u16)(qq[j] >> 16));
                    xr[i * 8 + j * 2]     = lo > 0.f ? lo : 0.f;
                    xr[i * 8 + j * 2 + 1] = hi > 0.f ? hi : 0.f;
                }
            }
        }
#pragma unroll
        for (int c = 0; c < HH; ++c) acc[c] = 0.f;
        if (valid) mm_uni<HH>(xr, Wlw, acc);
        coop_store_bf16(sbuf, t, acc, valid, nv, z_a + (size_t)row0 * HH);
    }
}

// ---------- L2 scatter: zb[dst] += z[src]*inv[dst] (cites+writes merged) ----------
__global__ __launch_bounds__(256) void scat2_k(
    const u16* __restrict__ zp, const u16* __restrict__ za,
    const int* __restrict__ cs, const int* __restrict__ cd,
    const int* __restrict__ wsrc, const int* __restrict__ wd,
    const float* __restrict__ inv_c, const float* __restrict__ inv_w,
    u32* __restrict__ zb) {
    int rel = blockIdx.y;
    const u16* y; const int* src; const int* dst; const float* inv;
    if (rel == 0) { y = zp; src = cs;   dst = cd; inv = inv_c; }
    else          { y = za; src = wsrc; dst = wd; inv = inv_w; }
    int t = threadIdx.x;
    int e = blockIdx.x * 16 + (t >> 4);
    int lane = t & 15;
    if (e >= NE) return;
    int s = src[e], d = dst[e];
    float iv = inv[d];
    u32 m = *(const u32*)(y + (size_t)s * HH + lane * 2);
    float lo = bf2f((u16)(m & 0xffffu)) * iv;
    float hi = bf2f((u16)(m >> 16)) * iv;
    pk_add_bf16(zb + (size_t)d * (HH / 2) + lane, lo, hi);
}

// ---------- final: out = hp2(f32 self) + zb(bf16 msg sums) ----------
__global__ __launch_bounds__(256) void final_k(
    const float* __restrict__ hp2, const u32* __restrict__ zb,
    float* __restrict__ out) {
    int i = blockIdx.x * 256 + threadIdx.x;   // one u32 = 2 channels
    if (i >= N_P * (HH / 2)) return;
    u32 z = zb[i];
    float2 h = *(const float2*)(hp2 + 2 * (size_t)i);
    float2 o = make_float2(h.x + bf2f((u16)(z & 0xffffu)),
                           h.y + bf2f((u16)(z >> 16)));
    *(float2*)(out + 2 * (size_t)i) = o;
}

extern "C" void kernel_launch(void* const* d_in, const int* in_sizes, int n_in,
                              void* d_out, int out_size, void* d_ws, size_t ws_size,
                              hipStream_t stream) {
    const float* x_p  = (const float*)d_in[0];
    const float* x_a  = (const float*)d_in[1];
    const int* c_src  = (const int*)d_in[2];
    const int* c_dst  = (const int*)d_in[3];
    const int* w_src  = (const int*)d_in[4];
    const int* w_dst  = (const int*)d_in[5];
    const int* r_src  = (const int*)d_in[6];
    const int* r_dst  = (const int*)d_in[7];
    const float* W1l_c = (const float*)d_in[8];
    const float* W1r_c = (const float*)d_in[9];
    const float* b1_c  = (const float*)d_in[10];
    const float* W1l_w = (const float*)d_in[11];
    const float* W1r_w = (const float*)d_in[12];
    const float* b1_w  = (const float*)d_in[13];
    const float* W1l_r = (const float*)d_in[14];
    const float* W1r_r = (const float*)d_in[15];
    const float* b1_r  = (const float*)d_in[16];
    const float* W2l_c = (const float*)d_in[17];
    const float* W2r_c = (const float*)d_in[18];
    const float* b2_c  = (const float*)d_in[19];
    const float* W2l_w = (const float*)d_in[20];
    const float* W2r_w = (const float*)d_in[21];
    const float* b2_w  = (const float*)d_in[22];

    // ---- workspace layout ----
    // [deg_c N_P][deg_w N_P][deg_r N_A][zb N_P*16 u32]  <- one memset(0) region
    // [W1s 2048][W2s 1024][b1s 32][b2s 32] f32
    // [hb_p N_P*32 u16][hb_a N_A*32 u16]
    // [y_pc N_P*32 u16][y_pr N_P*32 u16][y_aw N_A*32 u16]
    // [hp2 N_P*32 f32]                       total ~= 92 MB
    int* deg_c = (int*)d_ws;
    int* deg_w = deg_c + N_P;
    int* deg_r = deg_w + N_P;
    u32* zb    = (u32*)(deg_r + N_A);
    float* W1s = (float*)(zb + (size_t)N_P * (HH / 2));
    float* W2s = W1s + DD * HH;
    float* b1s = W2s + HH * HH;
    float* b2s = b1s + HH;
    u16* hb_p  = (u16*)(b2s + HH);
    u16* hb_a  = hb_p + (size_t)N_P * HH;
    u16* y_pc  = hb_a + (size_t)N_A * HH;
    u16* y_pr  = y_pc + (size_t)N_P * HH;
    u16* y_aw  = y_pr + (size_t)N_P * HH;
    float* hp2 = (float*)(y_aw + (size_t)N_A * HH);
    u16* z_p   = y_pc;   // reuse: y_pc dead after scat3
    u16* z_a   = y_aw;   // reuse: y_aw dead after scat3
    float* outp = (float*)d_out;

    const size_t need = ((uintptr_t)(hp2 + (size_t)N_P * HH)) - (uintptr_t)d_ws;
    if (ws_size < need) return;  // fail loudly, not OOB

    // zero degrees + L2 accumulator in one shot (contiguous)
    hipMemsetAsync(deg_c, 0,
                   (size_t)(2 * N_P + N_A) * sizeof(int)
                 + (size_t)N_P * (HH / 2) * sizeof(u32), stream);
    prep_sum_k<<<8, 256, 0, stream>>>(W1r_c, W1r_w, b1_c, b1_w, W2r_c, W2r_w, b2_c, b2_w,
                                      W1s, W2s, b1s, b2s);
    count3_k<<<dim3(EB, 3), 256, 0, stream>>>(c_dst, w_dst, r_dst, deg_c, deg_w, deg_r);
    deg2inv_k<<<(2 * N_P + N_A + 255) / 256, 256, 0, stream>>>(deg_c, 2 * N_P + N_A);
    const float* inv_c = (const float*)deg_c;
    const float* inv_w = (const float*)deg_w;
    const float* inv_r = (const float*)deg_r;

    t1_k<<<NBP + NBA, 256, 0, stream>>>(x_p, x_a, W1l_c, W1l_r, W1s, b1s,
                                        W1l_w, W1r_r, b1_r, y_pc, y_pr, y_aw, hb_p, hb_a);
    scat3_k<<<dim3(NE / 16, 3), 256, 0, stream>>>(y_pc, y_aw, y_pr,
                                                  c_src, c_dst, w_src, w_dst, r_src, r_dst,
                                                  inv_c, inv_w, inv_r,
                                                  (u32*)hb_p, (u32*)hb_a);
    t2_k<<<NBP + NBA, 256, 0, stream>>>((const u32*)hb_p, (const u32*)hb_a,
                                        W2l_c, W2s, b2s, W2l_w, z_p, z_a, hp2);
    scat2_k<<<dim3(NE / 16, 2), 256, 0, stream>>>(z_p, z_a, c_src, c_dst, w_src, w_dst,
                                                  inv_c, inv_w, zb);
    final_k<<<(N_P * (HH / 2) + 255) / 256, 256, 0, stream>>>(hp2, zb, outp);
}